// Round 7
// baseline (744.018 us; speedup 1.0000x reference)
//
#include <hip/hip_runtime.h>
#include <math.h>

// clDice loss on MI355X (gfx950).
// soft_skeletonize = 20 iterations of:
//   m = minpool3(x); contour = relu(maxpool3(m) - m); x = relu(x - contour)
// Round-17: LDS-residency fix. Round-6 post-mortem: BH 32->16 gave dur
// 120->168 us = exactly +40% (work ratio 1.43) with OccupancyPercent only
// 33->38 -- residency NEVER rose. 16.9KB x 4 = 67.6KB > 64KB: the
// co-schedulable LDS per CU behaves like 64KB, capping residency at 3
// blocks/CU at BOTH BH values (explains 33% < 50% ideal at BH=32 too).
// Latency-vs-issue still untested because the variable never moved.
// This round: single-buffered edge array + 2 barriers/row-iter
// (top barrier publishes prev-iter edge writes; mid barrier separates
// this iter's reads from writes). LDS 16.9 -> 8.4KB -> 7 blocks/CU,
// 28 waves/CU. BH stays 16 (grid supplies 8/CU). VGPR=60 <= 64 allows
// 8 waves/SIMD. Prediction: occupancy ~80%; if latency-bound dur ->
// ~80-95 us/launch; if flat with occupancy up -> issue-bound proven,
// revert BH=32 + instruction diet next.
// Structure otherwise: K=4 fused iters/launch, z=32 grid, cross-iter
// row prefetch, unroll-4 (ring renaming), per-block partials,
// 5 launches + finalize.

#define IMG_H 1024
#define IMG_W 1024
#define IMG_N (IMG_H * IMG_W)
#define NIMG  16
#define NZ    32                    // 16 pred + 16 gt images
#define BH    16                    // output rows per band
#define NBANDS (IMG_H / BH)         // 64
#define K     4                     // fused skeleton iterations per launch
#define EW    258                   // 256 lanes + 2 guard slots
#define NBLK  (NZ * NBANDS)         // 2048 blocks per launch
#define NITER (BH + 6 * K)          // 40 row-iterations

typedef _Float16 h2 __attribute__((ext_vector_type(2)));

__device__ __forceinline__ h2 hmin2(h2 a, h2 b) { return __builtin_elementwise_min(a, b); }
__device__ __forceinline__ h2 hmax2(h2 a, h2 b) { return __builtin_elementwise_max(a, b); }

union U32H { unsigned u; h2 h; };
__device__ __forceinline__ unsigned as_u(h2 h) { U32H t; t.h = h; return t.u; }
__device__ __forceinline__ h2 as_h2(unsigned u) { U32H t; t.u = u; return t.h; }

struct Hp { h2 lo, hi; };           // 4 image columns per lane
struct St { Hp hm1, hm2, m2, m3, q1, q2, x1, x2, x3, xc; };

// One pipeline stage. rmask: +inf pass / -inf force (maxpool row padding).
// Edge pair layout: e2[slot].x = {x_col0, m_col0} (read by LEFT-seeking
// neighbor at slot t+2); e2[slot].y = {x_col3, m_col3} (read at slot t).
// Single-buffered: caller guarantees a barrier between the previous
// iteration's writes and these reads, and between these reads and the
// next writes.
__device__ __forceinline__ Hp stage_step(
    St& s, h2 rmask, int t, const uint2 (&e2)[EW])
{
    h2 lp = as_h2(e2[t].y);        // left nbr's col3 {x, m}
    h2 rp = as_h2(e2[t + 2].x);    // right nbr's col0 {x, m}
    // h-min3 of x row
    h2 midx = (h2){s.xc.lo[1], s.xc.hi[0]};               // {x1, x2}
    h2 hlo = hmin2(hmin2((h2){lp[0], s.xc.lo[0]}, s.xc.lo), midx);
    h2 hhi = hmin2(hmin2(midx, s.xc.hi), (h2){s.xc.hi[1], rp[0]});
    // v-min3 + row-validity mask
    h2 mlo = hmin2(hmin2(hmin2(s.hm1.lo, s.hm2.lo), hlo), rmask);
    h2 mhi = hmin2(hmin2(hmin2(s.hm1.hi, s.hm2.hi), hhi), rmask);
    // h-max3 of m (previous iter's m, in m2; neighbor edges from LDS)
    h2 midm = (h2){s.m2.lo[1], s.m2.hi[0]};
    h2 qlo = hmax2(hmax2((h2){lp[1], s.m2.lo[0]}, s.m2.lo), midm);
    h2 qhi = hmax2(hmax2(midm, s.m2.hi), (h2){s.m2.hi[1], rp[1]});
    // v-max3
    h2 Mlo = hmax2(hmax2(s.q1.lo, s.q2.lo), qlo);
    h2 Mhi = hmax2(hmax2(s.q1.hi, s.q2.hi), qhi);
    // contour + relu update
    const h2 Z2 = (h2){(_Float16)0.f, (_Float16)0.f};
    h2 elo = hmax2(s.x3.lo - hmax2(Mlo - s.m3.lo, Z2), Z2);
    h2 ehi = hmax2(s.x3.hi - hmax2(Mhi - s.m3.hi, Z2), Z2);
    // ring shifts
    s.hm1 = s.hm2; s.hm2.lo = hlo; s.hm2.hi = hhi;
    s.m3  = s.m2;  s.m2.lo  = mlo; s.m2.hi  = mhi;
    s.q1  = s.q2;  s.q2.lo  = qlo; s.q2.hi  = qhi;
    s.x3  = s.x2;  s.x2 = s.x1;    s.x1 = s.xc;
    Hp e; e.lo = elo; e.hi = ehi;
    return e;
}

// Load one input row (or +inf outside the image). FIRST launch reads the
// f32 source and converts; later launches read the f16 intermediate.
template<int FIRST>
__device__ __forceinline__ Hp load_row(
    int y, int c, const float* __restrict__ f32src,
    const unsigned short* __restrict__ bsrc)
{
    const _Float16 HINF = (_Float16)__builtin_huge_valf();
    Hp x; x.lo = (h2){HINF, HINF}; x.hi = (h2){HINF, HINF};
    if ((unsigned)y < (unsigned)IMG_H) {
        if constexpr (FIRST) {
            float4 f = *(const float4*)(f32src + (size_t)y * IMG_W + c);
            x.lo = (h2){(_Float16)f.x, (_Float16)f.y};
            x.hi = (h2){(_Float16)f.z, (_Float16)f.w};
        } else {
            uint2 u = *(const uint2*)(bsrc + (size_t)y * IMG_W + c);
            x.lo = as_h2(u.x);
            x.hi = as_h2(u.y);
        }
    }
    return x;
}

template<int FIRST, int LAST>
__device__ __forceinline__ void iter_step(
    int y, int t, int c, int r0, St (&st)[K], Hp& xn,
    const float* __restrict__ f32src, const unsigned short* __restrict__ bsrc,
    unsigned short* __restrict__ bdst, const float* __restrict__ oth,
    float& a1, float& a2, uint2 (&e2)[K][EW])
{
    const _Float16 HINF = (_Float16)__builtin_huge_valf();
    const h2 PINF2 = (h2){HINF, HINF};
    const h2 NINF2 = (h2){-HINF, -HINF};

    // issue the row-(y+2) load now; its value is consumed NEXT iteration,
    // so the global-load latency spans a full iteration body.
    Hp tnext = load_row<FIRST>(y + 2, c, f32src, bsrc);

    __syncthreads();                         // prev-iter edge writes visible

    h2 rm = ((unsigned)(y - 13) < (unsigned)IMG_H) ? PINF2 : NINF2;
    Hp eK = stage_step(st[K - 1], rm, t, e2[K - 1]);
    #pragma unroll
    for (int k = K - 2; k >= 0; --k) {
        rm = ((unsigned)(y - 4 * k - 1) < (unsigned)IMG_H) ? PINF2 : NINF2;
        Hp e = stage_step(st[k], rm, t, e2[k]);
        h2 em = ((unsigned)(y - 4 * k - 3) < (unsigned)IMG_H) ? NINF2 : PINF2;
        st[k + 1].xc.lo = hmax2(e.lo, em);   // max(e,-inf)=e; max(e,+inf)=+inf
        st[k + 1].xc.hi = hmax2(e.hi, em);
    }
    st[0].xc = xn;                           // row y+1, loaded last iteration
    xn = tnext;

    __syncthreads();                         // all edge reads done

    // edge writes for next iteration (new xc + this iter's m, now in m2)
    #pragma unroll
    for (int k = 0; k < K; ++k) {
        e2[k][t + 1] = make_uint2(
            as_u((h2){st[k].xc.lo[0], st[k].m2.lo[0]}),
            as_u((h2){st[k].xc.hi[1], st[k].m2.hi[1]}));
    }

    int orow = y - (4 * (K - 1) + 3);        // y - 15
    if ((unsigned)(orow - r0) < (unsigned)BH) {
        if constexpr (!LAST) {
            *(uint2*)(bdst + (size_t)orow * IMG_W + c) =
                make_uint2(as_u(eK.lo), as_u(eK.hi));
        } else {
            float4 ov = *(const float4*)(oth + (size_t)orow * IMG_W + c);
            float e0 = (float)eK.lo[0], e1 = (float)eK.lo[1];
            float e2f = (float)eK.hi[0], e3 = (float)eK.hi[1];
            a1 += e0 * ov.x + e1 * ov.y + e2f * ov.z + e3 * ov.w;
            a2 += e0 + e1 + e2f + e3;
        }
    }
}

template<int FIRST, int LAST>
__global__ __attribute__((amdgpu_waves_per_eu(4, 8)))
__launch_bounds__(256) void skel(
    const unsigned short* __restrict__ src, unsigned short* __restrict__ dst,
    const float* __restrict__ pred32, const float* __restrict__ gt32,
    double* __restrict__ partials)
{
    __shared__ uint2 e2[K][EW];       // single-buffered edge exchange
    __shared__ double l1[4], l2[4];

    const int t = threadIdx.x, c = 4 * t;
    const int band = blockIdx.x, z = blockIdx.y;
    const int r0 = band * BH;
    const _Float16 HINF = (_Float16)__builtin_huge_valf();
    const h2 PINF2 = (h2){HINF, HINF};
    const h2 NINF2 = (h2){-HINF, -HINF};

    const float* f32src = (z < NIMG) ? pred32 + (size_t)z * IMG_N
                                     : gt32 + (size_t)(z - NIMG) * IMG_N;
    const unsigned short* bsrc = FIRST ? nullptr : src + (size_t)z * IMG_N;
    unsigned short* bdst = LAST ? nullptr : dst + (size_t)z * IMG_N;
    const float* oth = LAST ? ((z < NIMG) ? gt32 + (size_t)z * IMG_N
                                          : pred32 + (size_t)(z - NIMG) * IMG_N)
                            : nullptr;

    if (t < K) {
        // guard pairs: x=+inf (0x7C00 low), m=-inf (0xFC00 high)
        e2[t][0]      = make_uint2(0u, 0xFC007C00u);  // only .y read
        e2[t][EW - 1] = make_uint2(0xFC007C00u, 0u);  // only .x read
    }

    St st[K];
    #pragma unroll
    for (int k = 0; k < K; ++k) {
        st[k].hm1.lo = st[k].hm1.hi = PINF2;
        st[k].hm2.lo = st[k].hm2.hi = PINF2;
        st[k].m2.lo  = st[k].m2.hi  = NINF2;
        st[k].m3.lo  = st[k].m3.hi  = NINF2;
        st[k].q1.lo  = st[k].q1.hi  = NINF2;
        st[k].q2.lo  = st[k].q2.hi  = NINF2;
        st[k].x1.lo  = st[k].x1.hi  = PINF2;
        st[k].x2.lo  = st[k].x2.hi  = PINF2;
        st[k].x3.lo  = st[k].x3.hi  = PINF2;
        st[k].xc.lo  = st[k].xc.hi  = PINF2;
    }

    const int y0 = r0 - 2 * K;
    st[0].xc = load_row<FIRST>(y0, c, f32src, bsrc);
    Hp xn    = load_row<FIRST>(y0 + 1, c, f32src, bsrc);

    // prologue edge write (consumed by first iteration after its barrier)
    #pragma unroll
    for (int k = 0; k < K; ++k) {
        e2[k][t + 1] = make_uint2(
            as_u((h2){st[k].xc.lo[0], st[k].m2.lo[0]}),
            as_u((h2){st[k].xc.hi[1], st[k].m2.hi[1]}));
    }

    float a1 = 0.f, a2 = 0.f;
    // unroll 4 = x-ring period: ring-shift register copies vanish at the
    // loop back-edge.
    #pragma unroll 4
    for (int i = 0; i < NITER; ++i) {
        iter_step<FIRST, LAST>(y0 + i, t, c, r0, st, xn, f32src, bsrc, bdst, oth, a1, a2, e2);
    }

    if constexpr (LAST) {                    // per-block partials (no atomics)
        double d1 = a1, d2 = a2;
        for (int off = 32; off; off >>= 1) {
            d1 += __shfl_down(d1, off);
            d2 += __shfl_down(d2, off);
        }
        const int w = t >> 6;
        if ((t & 63) == 0) { l1[w] = d1; l2[w] = d2; }
        __syncthreads();
        if (t == 0) {
            int bid = z * NBANDS + band;
            partials[2 * bid]     = l1[0] + l1[1] + l1[2] + l1[3];
            partials[2 * bid + 1] = l2[0] + l2[1] + l2[2] + l2[3];
        }
    }
}

__global__ __launch_bounds__(256) void finalize(
    const double* __restrict__ pp, float* __restrict__ out)
{
    __shared__ double sh[4][4];
    double i1 = 0, i2 = 0, t1 = 0, t2 = 0;
    for (int i = threadIdx.x; i < NBLK; i += 256) {
        double a = pp[2 * i], b = pp[2 * i + 1];
        if (i < NIMG * NBANDS) { i1 += a; i2 += b; }   // z < 16: cl_pred side
        else                   { t1 += a; t2 += b; }   // z >= 16: skel_gt side
    }
    for (int off = 32; off; off >>= 1) {
        i1 += __shfl_down(i1, off); i2 += __shfl_down(i2, off);
        t1 += __shfl_down(t1, off); t2 += __shfl_down(t2, off);
    }
    const int w = threadIdx.x >> 6;
    if ((threadIdx.x & 63) == 0) { sh[0][w] = i1; sh[1][w] = i2; sh[2][w] = t1; sh[3][w] = t2; }
    __syncthreads();
    if (threadIdx.x == 0) {
        double s1 = 0, s2 = 0, s3 = 0, s4 = 0;
        for (int j = 0; j < 4; ++j) { s1 += sh[0][j]; s2 += sh[1][j]; s3 += sh[2][j]; s4 += sh[3][j]; }
        double iflat = (s1 + 1.0) / (s2 + 1.0);
        double tflat = (s3 + 1.0) / (s4 + 1.0);
        out[0] = (float)(1.0 - 2.0 * (iflat * tflat) / (iflat + tflat));
    }
}

extern "C" void kernel_launch(void* const* d_in, const int* in_sizes, int n_in,
                              void* d_out, int out_size, void* d_ws, size_t ws_size,
                              hipStream_t stream)
{
    const float* pred = (const float*)d_in[0];
    const float* gt   = (const float*)d_in[1];

    unsigned short* A = (unsigned short*)d_ws;            // 32 f16 images (64 MiB)
    unsigned short* B = A + (size_t)NZ * IMG_N;           // 32 f16 images
    double* partials  = (double*)d_ws;                    // overlaps A; A is dead
                                                          // when launch 5 (reads B) runs
    dim3 grid(NBANDS, NZ);                                // 64 bands x 32 images

    skel<1, 0><<<grid, 256, 0, stream>>>(nullptr, A, pred, gt, nullptr);  // iters 1-4
    skel<0, 0><<<grid, 256, 0, stream>>>(A, B, pred, gt, nullptr);        // 5-8
    skel<0, 0><<<grid, 256, 0, stream>>>(B, A, pred, gt, nullptr);        // 9-12
    skel<0, 0><<<grid, 256, 0, stream>>>(A, B, pred, gt, nullptr);        // 13-16
    skel<0, 1><<<grid, 256, 0, stream>>>(B, nullptr, pred, gt, partials); // 17-20 + sums

    finalize<<<1, 256, 0, stream>>>(partials, (float*)d_out);
}

// Round 8
// 582.763 us; speedup vs baseline: 1.2767x; 1.2767x over previous
//
#include <hip/hip_runtime.h>
#include <math.h>

// clDice loss on MI355X (gfx950).
// soft_skeletonize = 20 iterations of:
//   m = minpool3(x); contour = relu(maxpool3(m) - m); x = relu(x - contour)
// Round-18: BH=32 revert + interior-band mask elision.
// Evidence ledger: occupancy counter pinned at 33-38% across LDS
// 16.9->8.5KB and BH 32->16 (rounds 6/7) -> neither LDS nor VGPR caps
// residency; counter treated as unreliable. Instruction-stream changes
// are what move time (f16 pack -17%, unroll/prefetch -8%, r7 single-buf
// restructure -8%/iter); occupancy knobs move nothing. VALUBusy 65-72%.
// => issue-bound-ish. So: revert the +43%-work BH=16 (keep r7's better
// per-iter structure: single-buffered edges, 2 barriers/iter, unroll-4),
// and delete provably-constant mask ops for interior bands. All rm/em
// masks are IMAGE-boundary checks; for bands 1..30 every mask is
// constant (rm=+inf, em=-inf, loads in-bounds) incl. warm-up, since
// y-ranges [r0-21, r0+49] stay inside [0,1024). Bands 0/31 keep the
// verified masked path. Saves ~8 pk_min + ~6 pk_max/cndmask + load
// exec-masking per row-iter for 94% of blocks.
// Predicted: ~100-106 us/launch, total ~515-535; FETCH ~117MB; VGPR<=64.
// If <3% from elision: masks were scalar-cheap -> z-pair ILP next.

#define IMG_H 1024
#define IMG_W 1024
#define IMG_N (IMG_H * IMG_W)
#define NIMG  16
#define NZ    32                    // 16 pred + 16 gt images
#define BH    32                    // output rows per band
#define NBANDS (IMG_H / BH)         // 32
#define K     4                     // fused skeleton iterations per launch
#define EW    258                   // 256 lanes + 2 guard slots
#define NBLK  (NZ * NBANDS)         // 1024 blocks per launch
#define NITER (BH + 6 * K)          // 56 row-iterations

typedef _Float16 h2 __attribute__((ext_vector_type(2)));

__device__ __forceinline__ h2 hmin2(h2 a, h2 b) { return __builtin_elementwise_min(a, b); }
__device__ __forceinline__ h2 hmax2(h2 a, h2 b) { return __builtin_elementwise_max(a, b); }

union U32H { unsigned u; h2 h; };
__device__ __forceinline__ unsigned as_u(h2 h) { U32H t; t.h = h; return t.u; }
__device__ __forceinline__ h2 as_h2(unsigned u) { U32H t; t.u = u; return t.h; }

struct Hp { h2 lo, hi; };           // 4 image columns per lane
struct St { Hp hm1, hm2, m2, m3, q1, q2, x1, x2, x3, xc; };

// One pipeline stage. rmask: +inf pass / -inf force (maxpool row padding);
// only applied when MASKED (edge bands). Edge pair layout:
// e2[slot].x = {x_col0, m_col0} (read by LEFT-seeking neighbor at t+2);
// e2[slot].y = {x_col3, m_col3} (read at slot t). Single-buffered: caller
// guarantees barriers between prev writes / these reads / next writes.
template<int MASKED>
__device__ __forceinline__ Hp stage_step(
    St& s, h2 rmask, int t, const uint2 (&e2)[EW])
{
    h2 lp = as_h2(e2[t].y);        // left nbr's col3 {x, m}
    h2 rp = as_h2(e2[t + 2].x);    // right nbr's col0 {x, m}
    // h-min3 of x row
    h2 midx = (h2){s.xc.lo[1], s.xc.hi[0]};               // {x1, x2}
    h2 hlo = hmin2(hmin2((h2){lp[0], s.xc.lo[0]}, s.xc.lo), midx);
    h2 hhi = hmin2(hmin2(midx, s.xc.hi), (h2){s.xc.hi[1], rp[0]});
    // v-min3 (+ row-validity mask on edge bands only)
    h2 mlo, mhi;
    if constexpr (MASKED) {
        mlo = hmin2(hmin2(hmin2(s.hm1.lo, s.hm2.lo), hlo), rmask);
        mhi = hmin2(hmin2(hmin2(s.hm1.hi, s.hm2.hi), hhi), rmask);
    } else {
        mlo = hmin2(hmin2(s.hm1.lo, s.hm2.lo), hlo);
        mhi = hmin2(hmin2(s.hm1.hi, s.hm2.hi), hhi);
    }
    // h-max3 of m (previous iter's m, in m2; neighbor edges from LDS)
    h2 midm = (h2){s.m2.lo[1], s.m2.hi[0]};
    h2 qlo = hmax2(hmax2((h2){lp[1], s.m2.lo[0]}, s.m2.lo), midm);
    h2 qhi = hmax2(hmax2(midm, s.m2.hi), (h2){s.m2.hi[1], rp[1]});
    // v-max3
    h2 Mlo = hmax2(hmax2(s.q1.lo, s.q2.lo), qlo);
    h2 Mhi = hmax2(hmax2(s.q1.hi, s.q2.hi), qhi);
    // contour + relu update
    const h2 Z2 = (h2){(_Float16)0.f, (_Float16)0.f};
    h2 elo = hmax2(s.x3.lo - hmax2(Mlo - s.m3.lo, Z2), Z2);
    h2 ehi = hmax2(s.x3.hi - hmax2(Mhi - s.m3.hi, Z2), Z2);
    // ring shifts
    s.hm1 = s.hm2; s.hm2.lo = hlo; s.hm2.hi = hhi;
    s.m3  = s.m2;  s.m2.lo  = mlo; s.m2.hi  = mhi;
    s.q1  = s.q2;  s.q2.lo  = qlo; s.q2.hi  = qhi;
    s.x3  = s.x2;  s.x2 = s.x1;    s.x1 = s.xc;
    Hp e; e.lo = elo; e.hi = ehi;
    return e;
}

// Load one input row. MASKED: +inf outside the image. Unmasked (interior
// bands): every touched row is provably in-bounds -> unconditional load.
template<int FIRST, int MASKED>
__device__ __forceinline__ Hp load_row(
    int y, int c, const float* __restrict__ f32src,
    const unsigned short* __restrict__ bsrc)
{
    const _Float16 HINF = (_Float16)__builtin_huge_valf();
    Hp x; x.lo = (h2){HINF, HINF}; x.hi = (h2){HINF, HINF};
    if (!MASKED || (unsigned)y < (unsigned)IMG_H) {
        if constexpr (FIRST) {
            float4 f = *(const float4*)(f32src + (size_t)y * IMG_W + c);
            x.lo = (h2){(_Float16)f.x, (_Float16)f.y};
            x.hi = (h2){(_Float16)f.z, (_Float16)f.w};
        } else {
            uint2 u = *(const uint2*)(bsrc + (size_t)y * IMG_W + c);
            x.lo = as_h2(u.x);
            x.hi = as_h2(u.y);
        }
    }
    return x;
}

template<int FIRST, int LAST, int MASKED>
__device__ __forceinline__ void iter_step(
    int y, int t, int c, int r0, St (&st)[K], Hp& xn,
    const float* __restrict__ f32src, const unsigned short* __restrict__ bsrc,
    unsigned short* __restrict__ bdst, const float* __restrict__ oth,
    float& a1, float& a2, uint2 (&e2)[K][EW])
{
    const _Float16 HINF = (_Float16)__builtin_huge_valf();
    const h2 PINF2 = (h2){HINF, HINF};
    const h2 NINF2 = (h2){-HINF, -HINF};

    // issue the row-(y+2) load now; its value is consumed NEXT iteration,
    // so the global-load latency spans a full iteration body.
    Hp tnext = load_row<FIRST, MASKED>(y + 2, c, f32src, bsrc);

    __syncthreads();                         // prev-iter edge writes visible

    h2 rm = PINF2;
    if constexpr (MASKED)
        rm = ((unsigned)(y - 13) < (unsigned)IMG_H) ? PINF2 : NINF2;
    Hp eK = stage_step<MASKED>(st[K - 1], rm, t, e2[K - 1]);
    #pragma unroll
    for (int k = K - 2; k >= 0; --k) {
        if constexpr (MASKED)
            rm = ((unsigned)(y - 4 * k - 1) < (unsigned)IMG_H) ? PINF2 : NINF2;
        Hp e = stage_step<MASKED>(st[k], rm, t, e2[k]);
        if constexpr (MASKED) {
            h2 em = ((unsigned)(y - 4 * k - 3) < (unsigned)IMG_H) ? NINF2 : PINF2;
            st[k + 1].xc.lo = hmax2(e.lo, em);   // max(e,-inf)=e; max(e,+inf)=+inf
            st[k + 1].xc.hi = hmax2(e.hi, em);
        } else {
            st[k + 1].xc = e;
        }
    }
    st[0].xc = xn;                           // row y+1, loaded last iteration
    xn = tnext;

    __syncthreads();                         // all edge reads done

    // edge writes for next iteration (new xc + this iter's m, now in m2)
    #pragma unroll
    for (int k = 0; k < K; ++k) {
        e2[k][t + 1] = make_uint2(
            as_u((h2){st[k].xc.lo[0], st[k].m2.lo[0]}),
            as_u((h2){st[k].xc.hi[1], st[k].m2.hi[1]}));
    }

    int orow = y - (4 * (K - 1) + 3);        // y - 15
    if ((unsigned)(orow - r0) < (unsigned)BH) {
        if constexpr (!LAST) {
            *(uint2*)(bdst + (size_t)orow * IMG_W + c) =
                make_uint2(as_u(eK.lo), as_u(eK.hi));
        } else {
            float4 ov = *(const float4*)(oth + (size_t)orow * IMG_W + c);
            float e0 = (float)eK.lo[0], e1 = (float)eK.lo[1];
            float e2f = (float)eK.hi[0], e3 = (float)eK.hi[1];
            a1 += e0 * ov.x + e1 * ov.y + e2f * ov.z + e3 * ov.w;
            a2 += e0 + e1 + e2f + e3;
        }
    }
}

template<int FIRST, int LAST>
__global__ __attribute__((amdgpu_waves_per_eu(4, 8)))
__launch_bounds__(256) void skel(
    const unsigned short* __restrict__ src, unsigned short* __restrict__ dst,
    const float* __restrict__ pred32, const float* __restrict__ gt32,
    double* __restrict__ partials)
{
    __shared__ uint2 e2[K][EW];       // single-buffered edge exchange
    __shared__ double l1[4], l2[4];

    const int t = threadIdx.x, c = 4 * t;
    const int band = blockIdx.x, z = blockIdx.y;
    const int r0 = band * BH;
    const _Float16 HINF = (_Float16)__builtin_huge_valf();
    const h2 PINF2 = (h2){HINF, HINF};
    const h2 NINF2 = (h2){-HINF, -HINF};

    const float* f32src = (z < NIMG) ? pred32 + (size_t)z * IMG_N
                                     : gt32 + (size_t)(z - NIMG) * IMG_N;
    const unsigned short* bsrc = FIRST ? nullptr : src + (size_t)z * IMG_N;
    unsigned short* bdst = LAST ? nullptr : dst + (size_t)z * IMG_N;
    const float* oth = LAST ? ((z < NIMG) ? gt32 + (size_t)z * IMG_N
                                          : pred32 + (size_t)(z - NIMG) * IMG_N)
                            : nullptr;

    if (t < K) {
        // guard pairs: x=+inf (0x7C00 low), m=-inf (0xFC00 high)
        e2[t][0]      = make_uint2(0u, 0xFC007C00u);  // only .y read
        e2[t][EW - 1] = make_uint2(0xFC007C00u, 0u);  // only .x read
    }

    St st[K];
    #pragma unroll
    for (int k = 0; k < K; ++k) {
        st[k].hm1.lo = st[k].hm1.hi = PINF2;
        st[k].hm2.lo = st[k].hm2.hi = PINF2;
        st[k].m2.lo  = st[k].m2.hi  = NINF2;
        st[k].m3.lo  = st[k].m3.hi  = NINF2;
        st[k].q1.lo  = st[k].q1.hi  = NINF2;
        st[k].q2.lo  = st[k].q2.hi  = NINF2;
        st[k].x1.lo  = st[k].x1.hi  = PINF2;
        st[k].x2.lo  = st[k].x2.hi  = PINF2;
        st[k].x3.lo  = st[k].x3.hi  = PINF2;
        st[k].xc.lo  = st[k].xc.hi  = PINF2;
    }

    const int y0 = r0 - 2 * K;
    st[0].xc = load_row<FIRST, 1>(y0, c, f32src, bsrc);      // masked: cheap, once
    Hp xn    = load_row<FIRST, 1>(y0 + 1, c, f32src, bsrc);

    // prologue edge write (consumed by first iteration after its barrier)
    #pragma unroll
    for (int k = 0; k < K; ++k) {
        e2[k][t + 1] = make_uint2(
            as_u((h2){st[k].xc.lo[0], st[k].m2.lo[0]}),
            as_u((h2){st[k].xc.hi[1], st[k].m2.hi[1]}));
    }

    float a1 = 0.f, a2 = 0.f;
    // Interior bands (1..NBANDS-2): every rm/em mask and load bound is
    // provably constant across the whole y-range incl. warm-up
    // (y-ranges [r0-21, r0+49] within [0,1024)) -> maskless path.
    // unroll 4 = x-ring period: ring-shift copies vanish at back-edge.
    if (band >= 1 && band <= NBANDS - 2) {
        #pragma unroll 4
        for (int i = 0; i < NITER; ++i)
            iter_step<FIRST, LAST, 0>(y0 + i, t, c, r0, st, xn, f32src, bsrc, bdst, oth, a1, a2, e2);
    } else {
        #pragma unroll 4
        for (int i = 0; i < NITER; ++i)
            iter_step<FIRST, LAST, 1>(y0 + i, t, c, r0, st, xn, f32src, bsrc, bdst, oth, a1, a2, e2);
    }

    if constexpr (LAST) {                    // per-block partials (no atomics)
        double d1 = a1, d2 = a2;
        for (int off = 32; off; off >>= 1) {
            d1 += __shfl_down(d1, off);
            d2 += __shfl_down(d2, off);
        }
        const int w = t >> 6;
        if ((t & 63) == 0) { l1[w] = d1; l2[w] = d2; }
        __syncthreads();
        if (t == 0) {
            int bid = z * NBANDS + band;
            partials[2 * bid]     = l1[0] + l1[1] + l1[2] + l1[3];
            partials[2 * bid + 1] = l2[0] + l2[1] + l2[2] + l2[3];
        }
    }
}

__global__ __launch_bounds__(256) void finalize(
    const double* __restrict__ pp, float* __restrict__ out)
{
    __shared__ double sh[4][4];
    double i1 = 0, i2 = 0, t1 = 0, t2 = 0;
    for (int i = threadIdx.x; i < NBLK; i += 256) {
        double a = pp[2 * i], b = pp[2 * i + 1];
        if (i < NIMG * NBANDS) { i1 += a; i2 += b; }   // z < 16: cl_pred side
        else                   { t1 += a; t2 += b; }   // z >= 16: skel_gt side
    }
    for (int off = 32; off; off >>= 1) {
        i1 += __shfl_down(i1, off); i2 += __shfl_down(i2, off);
        t1 += __shfl_down(t1, off); t2 += __shfl_down(t2, off);
    }
    const int w = threadIdx.x >> 6;
    if ((threadIdx.x & 63) == 0) { sh[0][w] = i1; sh[1][w] = i2; sh[2][w] = t1; sh[3][w] = t2; }
    __syncthreads();
    if (threadIdx.x == 0) {
        double s1 = 0, s2 = 0, s3 = 0, s4 = 0;
        for (int j = 0; j < 4; ++j) { s1 += sh[0][j]; s2 += sh[1][j]; s3 += sh[2][j]; s4 += sh[3][j]; }
        double iflat = (s1 + 1.0) / (s2 + 1.0);
        double tflat = (s3 + 1.0) / (s4 + 1.0);
        out[0] = (float)(1.0 - 2.0 * (iflat * tflat) / (iflat + tflat));
    }
}

extern "C" void kernel_launch(void* const* d_in, const int* in_sizes, int n_in,
                              void* d_out, int out_size, void* d_ws, size_t ws_size,
                              hipStream_t stream)
{
    const float* pred = (const float*)d_in[0];
    const float* gt   = (const float*)d_in[1];

    unsigned short* A = (unsigned short*)d_ws;            // 32 f16 images (64 MiB)
    unsigned short* B = A + (size_t)NZ * IMG_N;           // 32 f16 images
    double* partials  = (double*)d_ws;                    // overlaps A; A is dead
                                                          // when launch 5 (reads B) runs
    dim3 grid(NBANDS, NZ);                                // 32 bands x 32 images

    skel<1, 0><<<grid, 256, 0, stream>>>(nullptr, A, pred, gt, nullptr);  // iters 1-4
    skel<0, 0><<<grid, 256, 0, stream>>>(A, B, pred, gt, nullptr);        // 5-8
    skel<0, 0><<<grid, 256, 0, stream>>>(B, A, pred, gt, nullptr);        // 9-12
    skel<0, 0><<<grid, 256, 0, stream>>>(A, B, pred, gt, nullptr);        // 13-16
    skel<0, 1><<<grid, 256, 0, stream>>>(B, nullptr, pred, gt, partials); // 17-20 + sums

    finalize<<<1, 256, 0, stream>>>(partials, (float*)d_out);
}

// Round 9
// 561.267 us; speedup vs baseline: 1.3256x; 1.0383x over previous
//
#include <hip/hip_runtime.h>
#include <math.h>

// clDice loss on MI355X (gfx950).
// soft_skeletonize = 20 iterations of:
//   m = minpool3(x); contour = relu(maxpool3(m) - m); x = relu(x - contour)
// Round-19: BH=64 halo-amortization probe. Ledger: occupancy counter
// pinned at 29-38% (~2.4-3 blocks/CU) across EVERY config (4 or 8
// blocks/CU offered, LDS 16.9/8.5KB, VGPR 60-64) and per-iter time never
// moved -> real residency ~2-3 blocks/CU regardless of what we offer.
// If so, warm-up halo (6K=24 rows/band, fixed) is the lever: BH 32->64
// cuts per-image row-iters 32x56=1792 -> 16x88=1408 (-21.4% work).
// Single variable vs round-8; per-iter engine unchanged (single-buffered
// edges, 2 barriers/iter, unroll-4 ring renaming, interior-band mask
// elision, K=4, cross-iter prefetch, 5 launches + finalize).
// Predicted: ~90-95 us/launch, total ~460-485; FETCH ~93MB; VGPR 64.
// Failure: >=115 us -> 2 blocks/CU below latency knee -> revert BH=32,
// pivot to z-pair ILP.

#define IMG_H 1024
#define IMG_W 1024
#define IMG_N (IMG_H * IMG_W)
#define NIMG  16
#define NZ    32                    // 16 pred + 16 gt images
#define BH    64                    // output rows per band
#define NBANDS (IMG_H / BH)         // 16
#define K     4                     // fused skeleton iterations per launch
#define EW    258                   // 256 lanes + 2 guard slots
#define NBLK  (NZ * NBANDS)         // 512 blocks per launch
#define NITER (BH + 6 * K)          // 88 row-iterations

typedef _Float16 h2 __attribute__((ext_vector_type(2)));

__device__ __forceinline__ h2 hmin2(h2 a, h2 b) { return __builtin_elementwise_min(a, b); }
__device__ __forceinline__ h2 hmax2(h2 a, h2 b) { return __builtin_elementwise_max(a, b); }

union U32H { unsigned u; h2 h; };
__device__ __forceinline__ unsigned as_u(h2 h) { U32H t; t.h = h; return t.u; }
__device__ __forceinline__ h2 as_h2(unsigned u) { U32H t; t.u = u; return t.h; }

struct Hp { h2 lo, hi; };           // 4 image columns per lane
struct St { Hp hm1, hm2, m2, m3, q1, q2, x1, x2, x3, xc; };

// One pipeline stage. rmask: +inf pass / -inf force (maxpool row padding);
// only applied when MASKED (edge bands). Edge pair layout:
// e2[slot].x = {x_col0, m_col0} (read by LEFT-seeking neighbor at t+2);
// e2[slot].y = {x_col3, m_col3} (read at slot t). Single-buffered: caller
// guarantees barriers between prev writes / these reads / next writes.
template<int MASKED>
__device__ __forceinline__ Hp stage_step(
    St& s, h2 rmask, int t, const uint2 (&e2)[EW])
{
    h2 lp = as_h2(e2[t].y);        // left nbr's col3 {x, m}
    h2 rp = as_h2(e2[t + 2].x);    // right nbr's col0 {x, m}
    // h-min3 of x row
    h2 midx = (h2){s.xc.lo[1], s.xc.hi[0]};               // {x1, x2}
    h2 hlo = hmin2(hmin2((h2){lp[0], s.xc.lo[0]}, s.xc.lo), midx);
    h2 hhi = hmin2(hmin2(midx, s.xc.hi), (h2){s.xc.hi[1], rp[0]});
    // v-min3 (+ row-validity mask on edge bands only)
    h2 mlo, mhi;
    if constexpr (MASKED) {
        mlo = hmin2(hmin2(hmin2(s.hm1.lo, s.hm2.lo), hlo), rmask);
        mhi = hmin2(hmin2(hmin2(s.hm1.hi, s.hm2.hi), hhi), rmask);
    } else {
        mlo = hmin2(hmin2(s.hm1.lo, s.hm2.lo), hlo);
        mhi = hmin2(hmin2(s.hm1.hi, s.hm2.hi), hhi);
    }
    // h-max3 of m (previous iter's m, in m2; neighbor edges from LDS)
    h2 midm = (h2){s.m2.lo[1], s.m2.hi[0]};
    h2 qlo = hmax2(hmax2((h2){lp[1], s.m2.lo[0]}, s.m2.lo), midm);
    h2 qhi = hmax2(hmax2(midm, s.m2.hi), (h2){s.m2.hi[1], rp[1]});
    // v-max3
    h2 Mlo = hmax2(hmax2(s.q1.lo, s.q2.lo), qlo);
    h2 Mhi = hmax2(hmax2(s.q1.hi, s.q2.hi), qhi);
    // contour + relu update
    const h2 Z2 = (h2){(_Float16)0.f, (_Float16)0.f};
    h2 elo = hmax2(s.x3.lo - hmax2(Mlo - s.m3.lo, Z2), Z2);
    h2 ehi = hmax2(s.x3.hi - hmax2(Mhi - s.m3.hi, Z2), Z2);
    // ring shifts
    s.hm1 = s.hm2; s.hm2.lo = hlo; s.hm2.hi = hhi;
    s.m3  = s.m2;  s.m2.lo  = mlo; s.m2.hi  = mhi;
    s.q1  = s.q2;  s.q2.lo  = qlo; s.q2.hi  = qhi;
    s.x3  = s.x2;  s.x2 = s.x1;    s.x1 = s.xc;
    Hp e; e.lo = elo; e.hi = ehi;
    return e;
}

// Load one input row. MASKED: +inf outside the image. Unmasked (interior
// bands): every touched row is provably in-bounds -> unconditional load.
template<int FIRST, int MASKED>
__device__ __forceinline__ Hp load_row(
    int y, int c, const float* __restrict__ f32src,
    const unsigned short* __restrict__ bsrc)
{
    const _Float16 HINF = (_Float16)__builtin_huge_valf();
    Hp x; x.lo = (h2){HINF, HINF}; x.hi = (h2){HINF, HINF};
    if (!MASKED || (unsigned)y < (unsigned)IMG_H) {
        if constexpr (FIRST) {
            float4 f = *(const float4*)(f32src + (size_t)y * IMG_W + c);
            x.lo = (h2){(_Float16)f.x, (_Float16)f.y};
            x.hi = (h2){(_Float16)f.z, (_Float16)f.w};
        } else {
            uint2 u = *(const uint2*)(bsrc + (size_t)y * IMG_W + c);
            x.lo = as_h2(u.x);
            x.hi = as_h2(u.y);
        }
    }
    return x;
}

template<int FIRST, int LAST, int MASKED>
__device__ __forceinline__ void iter_step(
    int y, int t, int c, int r0, St (&st)[K], Hp& xn,
    const float* __restrict__ f32src, const unsigned short* __restrict__ bsrc,
    unsigned short* __restrict__ bdst, const float* __restrict__ oth,
    float& a1, float& a2, uint2 (&e2)[K][EW])
{
    const _Float16 HINF = (_Float16)__builtin_huge_valf();
    const h2 PINF2 = (h2){HINF, HINF};
    const h2 NINF2 = (h2){-HINF, -HINF};

    // issue the row-(y+2) load now; its value is consumed NEXT iteration,
    // so the global-load latency spans a full iteration body.
    Hp tnext = load_row<FIRST, MASKED>(y + 2, c, f32src, bsrc);

    __syncthreads();                         // prev-iter edge writes visible

    h2 rm = PINF2;
    if constexpr (MASKED)
        rm = ((unsigned)(y - 13) < (unsigned)IMG_H) ? PINF2 : NINF2;
    Hp eK = stage_step<MASKED>(st[K - 1], rm, t, e2[K - 1]);
    #pragma unroll
    for (int k = K - 2; k >= 0; --k) {
        if constexpr (MASKED)
            rm = ((unsigned)(y - 4 * k - 1) < (unsigned)IMG_H) ? PINF2 : NINF2;
        Hp e = stage_step<MASKED>(st[k], rm, t, e2[k]);
        if constexpr (MASKED) {
            h2 em = ((unsigned)(y - 4 * k - 3) < (unsigned)IMG_H) ? NINF2 : PINF2;
            st[k + 1].xc.lo = hmax2(e.lo, em);   // max(e,-inf)=e; max(e,+inf)=+inf
            st[k + 1].xc.hi = hmax2(e.hi, em);
        } else {
            st[k + 1].xc = e;
        }
    }
    st[0].xc = xn;                           // row y+1, loaded last iteration
    xn = tnext;

    __syncthreads();                         // all edge reads done

    // edge writes for next iteration (new xc + this iter's m, now in m2)
    #pragma unroll
    for (int k = 0; k < K; ++k) {
        e2[k][t + 1] = make_uint2(
            as_u((h2){st[k].xc.lo[0], st[k].m2.lo[0]}),
            as_u((h2){st[k].xc.hi[1], st[k].m2.hi[1]}));
    }

    int orow = y - (4 * (K - 1) + 3);        // y - 15
    if ((unsigned)(orow - r0) < (unsigned)BH) {
        if constexpr (!LAST) {
            *(uint2*)(bdst + (size_t)orow * IMG_W + c) =
                make_uint2(as_u(eK.lo), as_u(eK.hi));
        } else {
            float4 ov = *(const float4*)(oth + (size_t)orow * IMG_W + c);
            float e0 = (float)eK.lo[0], e1 = (float)eK.lo[1];
            float e2f = (float)eK.hi[0], e3 = (float)eK.hi[1];
            a1 += e0 * ov.x + e1 * ov.y + e2f * ov.z + e3 * ov.w;
            a2 += e0 + e1 + e2f + e3;
        }
    }
}

template<int FIRST, int LAST>
__global__ __attribute__((amdgpu_waves_per_eu(4, 8)))
__launch_bounds__(256) void skel(
    const unsigned short* __restrict__ src, unsigned short* __restrict__ dst,
    const float* __restrict__ pred32, const float* __restrict__ gt32,
    double* __restrict__ partials)
{
    __shared__ uint2 e2[K][EW];       // single-buffered edge exchange
    __shared__ double l1[4], l2[4];

    const int t = threadIdx.x, c = 4 * t;
    const int band = blockIdx.x, z = blockIdx.y;
    const int r0 = band * BH;
    const _Float16 HINF = (_Float16)__builtin_huge_valf();
    const h2 PINF2 = (h2){HINF, HINF};
    const h2 NINF2 = (h2){-HINF, -HINF};

    const float* f32src = (z < NIMG) ? pred32 + (size_t)z * IMG_N
                                     : gt32 + (size_t)(z - NIMG) * IMG_N;
    const unsigned short* bsrc = FIRST ? nullptr : src + (size_t)z * IMG_N;
    unsigned short* bdst = LAST ? nullptr : dst + (size_t)z * IMG_N;
    const float* oth = LAST ? ((z < NIMG) ? gt32 + (size_t)z * IMG_N
                                          : pred32 + (size_t)(z - NIMG) * IMG_N)
                            : nullptr;

    if (t < K) {
        // guard pairs: x=+inf (0x7C00 low), m=-inf (0xFC00 high)
        e2[t][0]      = make_uint2(0u, 0xFC007C00u);  // only .y read
        e2[t][EW - 1] = make_uint2(0xFC007C00u, 0u);  // only .x read
    }

    St st[K];
    #pragma unroll
    for (int k = 0; k < K; ++k) {
        st[k].hm1.lo = st[k].hm1.hi = PINF2;
        st[k].hm2.lo = st[k].hm2.hi = PINF2;
        st[k].m2.lo  = st[k].m2.hi  = NINF2;
        st[k].m3.lo  = st[k].m3.hi  = NINF2;
        st[k].q1.lo  = st[k].q1.hi  = NINF2;
        st[k].q2.lo  = st[k].q2.hi  = NINF2;
        st[k].x1.lo  = st[k].x1.hi  = PINF2;
        st[k].x2.lo  = st[k].x2.hi  = PINF2;
        st[k].x3.lo  = st[k].x3.hi  = PINF2;
        st[k].xc.lo  = st[k].xc.hi  = PINF2;
    }

    const int y0 = r0 - 2 * K;
    st[0].xc = load_row<FIRST, 1>(y0, c, f32src, bsrc);      // masked: cheap, once
    Hp xn    = load_row<FIRST, 1>(y0 + 1, c, f32src, bsrc);

    // prologue edge write (consumed by first iteration after its barrier)
    #pragma unroll
    for (int k = 0; k < K; ++k) {
        e2[k][t + 1] = make_uint2(
            as_u((h2){st[k].xc.lo[0], st[k].m2.lo[0]}),
            as_u((h2){st[k].xc.hi[1], st[k].m2.hi[1]}));
    }

    float a1 = 0.f, a2 = 0.f;
    // Interior bands (1..NBANDS-2): every rm/em mask and load bound is
    // provably constant across the whole y-range incl. warm-up
    // (y-ranges [r0-21, r0+81] within [0,1024) for r0 in [64, 896]).
    // unroll 4 = x-ring period: ring-shift copies vanish at back-edge.
    if (band >= 1 && band <= NBANDS - 2) {
        #pragma unroll 4
        for (int i = 0; i < NITER; ++i)
            iter_step<FIRST, LAST, 0>(y0 + i, t, c, r0, st, xn, f32src, bsrc, bdst, oth, a1, a2, e2);
    } else {
        #pragma unroll 4
        for (int i = 0; i < NITER; ++i)
            iter_step<FIRST, LAST, 1>(y0 + i, t, c, r0, st, xn, f32src, bsrc, bdst, oth, a1, a2, e2);
    }

    if constexpr (LAST) {                    // per-block partials (no atomics)
        double d1 = a1, d2 = a2;
        for (int off = 32; off; off >>= 1) {
            d1 += __shfl_down(d1, off);
            d2 += __shfl_down(d2, off);
        }
        const int w = t >> 6;
        if ((t & 63) == 0) { l1[w] = d1; l2[w] = d2; }
        __syncthreads();
        if (t == 0) {
            int bid = z * NBANDS + band;
            partials[2 * bid]     = l1[0] + l1[1] + l1[2] + l1[3];
            partials[2 * bid + 1] = l2[0] + l2[1] + l2[2] + l2[3];
        }
    }
}

__global__ __launch_bounds__(256) void finalize(
    const double* __restrict__ pp, float* __restrict__ out)
{
    __shared__ double sh[4][4];
    double i1 = 0, i2 = 0, t1 = 0, t2 = 0;
    for (int i = threadIdx.x; i < NBLK; i += 256) {
        double a = pp[2 * i], b = pp[2 * i + 1];
        if (i < NIMG * NBANDS) { i1 += a; i2 += b; }   // z < 16: cl_pred side
        else                   { t1 += a; t2 += b; }   // z >= 16: skel_gt side
    }
    for (int off = 32; off; off >>= 1) {
        i1 += __shfl_down(i1, off); i2 += __shfl_down(i2, off);
        t1 += __shfl_down(t1, off); t2 += __shfl_down(t2, off);
    }
    const int w = threadIdx.x >> 6;
    if ((threadIdx.x & 63) == 0) { sh[0][w] = i1; sh[1][w] = i2; sh[2][w] = t1; sh[3][w] = t2; }
    __syncthreads();
    if (threadIdx.x == 0) {
        double s1 = 0, s2 = 0, s3 = 0, s4 = 0;
        for (int j = 0; j < 4; ++j) { s1 += sh[0][j]; s2 += sh[1][j]; s3 += sh[2][j]; s4 += sh[3][j]; }
        double iflat = (s1 + 1.0) / (s2 + 1.0);
        double tflat = (s3 + 1.0) / (s4 + 1.0);
        out[0] = (float)(1.0 - 2.0 * (iflat * tflat) / (iflat + tflat));
    }
}

extern "C" void kernel_launch(void* const* d_in, const int* in_sizes, int n_in,
                              void* d_out, int out_size, void* d_ws, size_t ws_size,
                              hipStream_t stream)
{
    const float* pred = (const float*)d_in[0];
    const float* gt   = (const float*)d_in[1];

    unsigned short* A = (unsigned short*)d_ws;            // 32 f16 images (64 MiB)
    unsigned short* B = A + (size_t)NZ * IMG_N;           // 32 f16 images
    double* partials  = (double*)d_ws;                    // overlaps A; A is dead
                                                          // when launch 5 (reads B) runs
    dim3 grid(NBANDS, NZ);                                // 16 bands x 32 images

    skel<1, 0><<<grid, 256, 0, stream>>>(nullptr, A, pred, gt, nullptr);  // iters 1-4
    skel<0, 0><<<grid, 256, 0, stream>>>(A, B, pred, gt, nullptr);        // 5-8
    skel<0, 0><<<grid, 256, 0, stream>>>(B, A, pred, gt, nullptr);        // 9-12
    skel<0, 0><<<grid, 256, 0, stream>>>(A, B, pred, gt, nullptr);        // 13-16
    skel<0, 1><<<grid, 256, 0, stream>>>(B, nullptr, pred, gt, partials); // 17-20 + sums

    finalize<<<1, 256, 0, stream>>>(partials, (float*)d_out);
}